// Round 9
// baseline (205.884 us; speedup 1.0000x reference)
//
#include <hip/hip_runtime.h>

#define LQ     21760
#define NBATCH 2
#define MROWS  (NBATCH * LQ)   // 43520 rows for all GEMMs

typedef __attribute__((ext_vector_type(8))) short bf16x8;
typedef __attribute__((ext_vector_type(4))) float f32x4;

__device__ __forceinline__ unsigned short f2bf(float f) {
    unsigned u = __builtin_bit_cast(unsigned, f);
    return (unsigned short)((u + 0x7fffu + ((u >> 16) & 1u)) >> 16);  // RNE
}
__device__ __forceinline__ float bf2f(unsigned short h) {
    return __builtin_bit_cast(float, (unsigned)h << 16);
}
__device__ __forceinline__ float f16lo(unsigned u) {
    return (float)__builtin_bit_cast(_Float16, (unsigned short)(u & 0xffffu));
}
__device__ __forceinline__ float f16hi(unsigned u) {
    return (float)__builtin_bit_cast(_Float16, (unsigned short)(u >> 16));
}

// DPP row-rotate (within 16-lane rows) on the VALU pipe — no DS traffic.
template <int CTRL>
__device__ __forceinline__ float fdpp(float v) {
    int r = __builtin_amdgcn_update_dpp(
        0, __builtin_bit_cast(int, v), CTRL, 0xf, 0xf, false);
    return __builtin_bit_cast(float, r);
}

// ---------------------------------------------------------------------------
// All four weight matrices: W[256][N] fp32 -> Wt[N][256] bf16, one launch.
// ---------------------------------------------------------------------------
__global__ __launch_bounds__(256) void cvt_wall(
    const float* __restrict__ Wv, const float* __restrict__ Wo,
    const float* __restrict__ Wa, const float* __restrict__ Wu,
    short* __restrict__ Wtv, short* __restrict__ Wcat, short* __restrict__ Wtu)
{
    int idx = blockIdx.x * 256 + threadIdx.x;
    if (idx < 65536) {
        int nn = idx >> 8, k = idx & 255;
        Wtv[idx] = (short)f2bf(Wv[k * 256 + nn]);
    } else if (idx < 131072) {
        int j = idx - 65536; int nn = j >> 8, k = j & 255;
        Wcat[j] = (short)f2bf(Wo[k * 256 + nn]);
    } else if (idx < 163840) {
        int j = idx - 131072; int nn = j >> 8, k = j & 255;
        Wcat[65536 + j] = (short)f2bf(Wa[k * 128 + nn]);
    } else if (idx < 229376) {
        int j = idx - 163840; int nn = j >> 8, k = j & 255;
        Wtu[j] = (short)f2bf(Wu[k * 256 + nn]);
    }
}

// ---------------------------------------------------------------------------
// MFMA GEMM: C[M x N] = A[M x 256] * Bt[N x 256]^T + bias
// Tile 128x128, 4 waves (2x2), BK=64, K=256 fixed.
// AF32=1: A fp32, converted to bf16 during LDS staging (v_cvt_pk_bf16_f32).
// OMODE: 0 = f32 out, 1 = bf16 out, 2 = f16 out, 3 = split off/attn (N=384).
// ---------------------------------------------------------------------------
template <int AF32, int OMODE>
__global__ __launch_bounds__(256) void gemm_mfma(
    const void* __restrict__ Aptr,
    const short* __restrict__ Bt,
    const float* __restrict__ bias,
    const float* __restrict__ bias2,
    void* __restrict__ Cout,
    void* __restrict__ Cout2,
    int N)
{
    __shared__ short Al[128 * 64];
    __shared__ short Bl[128 * 64];

    const int tid  = threadIdx.x;
    const int lane = tid & 63, wid = tid >> 6;
    const int wr = wid >> 1, wc = wid & 1;
    const int bx = blockIdx.x, by = blockIdx.y;

    const long arow0 = (long)by * 128;
    const int  brow0 = bx * 128;

    const short* Abf = (const short*)Aptr;
    const float* Af  = (const float*)Aptr;

    f32x4 acc[4][4];
#pragma unroll
    for (int i = 0; i < 4; ++i)
#pragma unroll
        for (int j = 0; j < 4; ++j) acc[i][j] = (f32x4)0.f;

    bf16x8 ra[4], rb[4];
    float4 raf[4][2];

#pragma unroll
    for (int i = 0; i < 4; ++i) {
        int id = tid + i * 256, r = id >> 3, c = id & 7;
        if (AF32) {
            raf[i][0] = *(const float4*)(Af + (arow0 + r) * 256 + c * 8);
            raf[i][1] = *(const float4*)(Af + (arow0 + r) * 256 + c * 8 + 4);
        } else {
            ra[i] = *(const bf16x8*)(Abf + (arow0 + r) * 256 + c * 8);
        }
        rb[i] = *(const bf16x8*)(Bt + (long)(brow0 + r) * 256 + c * 8);
    }

    for (int step = 0; step < 4; ++step) {
#pragma unroll
        for (int i = 0; i < 4; ++i) {
            int id = tid + i * 256, r = id >> 3, c = id & 7;
            bf16x8 av;
            if (AF32) {
                unsigned q0, q1, q2, q3;
                asm("v_cvt_pk_bf16_f32 %0, %1, %2" : "=v"(q0) : "v"(raf[i][0].x), "v"(raf[i][0].y));
                asm("v_cvt_pk_bf16_f32 %0, %1, %2" : "=v"(q1) : "v"(raf[i][0].z), "v"(raf[i][0].w));
                asm("v_cvt_pk_bf16_f32 %0, %1, %2" : "=v"(q2) : "v"(raf[i][1].x), "v"(raf[i][1].y));
                asm("v_cvt_pk_bf16_f32 %0, %1, %2" : "=v"(q3) : "v"(raf[i][1].z), "v"(raf[i][1].w));
                uint4 u = make_uint4(q0, q1, q2, q3);
                av = __builtin_bit_cast(bf16x8, u);
            } else {
                av = ra[i];
            }
            *(bf16x8*)(Al + r * 64 + ((c ^ (r & 7)) * 8)) = av;
            *(bf16x8*)(Bl + r * 64 + ((c ^ (r & 7)) * 8)) = rb[i];
        }
        __syncthreads();
        if (step < 3) {
            const int k0 = (step + 1) * 64;
#pragma unroll
            for (int i = 0; i < 4; ++i) {
                int id = tid + i * 256, r = id >> 3, c = id & 7;
                if (AF32) {
                    raf[i][0] = *(const float4*)(Af + (arow0 + r) * 256 + k0 + c * 8);
                    raf[i][1] = *(const float4*)(Af + (arow0 + r) * 256 + k0 + c * 8 + 4);
                } else {
                    ra[i] = *(const bf16x8*)(Abf + (arow0 + r) * 256 + k0 + c * 8);
                }
                rb[i] = *(const bf16x8*)(Bt + (long)(brow0 + r) * 256 + k0 + c * 8);
            }
        }
#pragma unroll
        for (int kk = 0; kk < 2; ++kk) {
            const int g = lane >> 4;
            const int chunk = kk * 4 + g;
            bf16x8 af[4], bg[4];
#pragma unroll
            for (int mi = 0; mi < 4; ++mi) {
                int r = wr * 64 + mi * 16 + (lane & 15);
                af[mi] = *(const bf16x8*)(Al + r * 64 + ((chunk ^ (r & 7)) * 8));
            }
#pragma unroll
            for (int ni = 0; ni < 4; ++ni) {
                int r = wc * 64 + ni * 16 + (lane & 15);
                bg[ni] = *(const bf16x8*)(Bl + r * 64 + ((chunk ^ (r & 7)) * 8));
            }
#pragma unroll
            for (int mi = 0; mi < 4; ++mi)
#pragma unroll
                for (int ni = 0; ni < 4; ++ni)
                    acc[mi][ni] = __builtin_amdgcn_mfma_f32_16x16x32_bf16(
                        af[mi], bg[ni], acc[mi][ni], 0, 0, 0);
        }
        __syncthreads();
    }

#pragma unroll
    for (int mi = 0; mi < 4; ++mi) {
#pragma unroll
        for (int ni = 0; ni < 4; ++ni) {
            const int  col = bx * 128 + wc * 64 + ni * 16 + (lane & 15);
            const long row = (long)by * 128 + wr * 64 + mi * 16 + ((lane >> 4) * 4);
            float b;
            if (OMODE == 3) b = (col < 256) ? bias[col] : bias2[col - 256];
            else            b = bias[col];
#pragma unroll
            for (int q = 0; q < 4; ++q) {
                float v = acc[mi][ni][q] + b;
                if (OMODE == 0) {
                    ((float*)Cout)[(row + q) * N + col] = v;
                } else if (OMODE == 1) {
                    ((unsigned short*)Cout)[(row + q) * N + col] = f2bf(v);
                } else if (OMODE == 2) {
                    ((unsigned short*)Cout)[(row + q) * N + col] =
                        __builtin_bit_cast(unsigned short, (_Float16)v);
                } else {
                    if (col < 256)
                        ((unsigned short*)Cout)[(row + q) * 256 + col] = f2bf(v);
                    else
                        ((unsigned short*)Cout2)[(row + q) * 128 + (col - 256)] = f2bf(v);
                }
            }
        }
    }
}

// ---------------------------------------------------------------------------
// Fused softmax + sampling; value in fp16.
// Request-minimized consumer: lane = q4(0..3) + 4*cslot(0..15);
// 4 gather instructions x dwordx4 (16B/lane) cover all 64 corner-lines
// (was 8 x 8B): halves the divergent TA/L1 lane-request count.
// Reduce over cslot: 2 DPP row_ror folds + 32B LDS exchange.
// ---------------------------------------------------------------------------
__global__ __launch_bounds__(256, 8) void ms_sample_f16v(
    const unsigned short* __restrict__ valuef16, // (43520, 8, 32) f16
    const unsigned short* __restrict__ offbf,    // (43520, 256) bf16
    const unsigned short* __restrict__ attnbf,   // (43520, 128) bf16
    const float* __restrict__ refpts,            // (43520, 4, 2)
    unsigned short* __restrict__ accbf)          // (43520, 256) bf16
{
    __shared__ unsigned meta_lds[4][64];   // 1 KB
    __shared__ float    part[4][64][8];    // 8 KB

    const int lane = threadIdx.x & 63;
    const int wid  = threadIdx.x >> 6;
    const int b    = blockIdx.x;
    const int m    = b & 7;                 // block-uniform head
    const int qn   = (b >> 3) * 4 + wid;    // 0..43519
    const int n    = (qn >= LQ) ? 1 : 0;

    // ---------------- producer: lane = p + 16*c ----------------
    const int p   = lane & 15;              // point 0..15 (within DPP row)
    const int c   = lane >> 4;              // corner 0..3 (row id)
    const int cx  = c & 1, cy = c >> 1;
    const int lvl = p >> 2;
    const int pt  = p & 3;

    float lg = bf2f(attnbf[qn * 128 + m * 16 + p]);

    // softmax max+sum over the 16 p-lanes of this row, pure DPP (VALU)
    float mx = lg;
    mx = fmaxf(mx, fdpp<0x128>(mx));   // ror:8
    mx = fmaxf(mx, fdpp<0x124>(mx));   // ror:4
    mx = fmaxf(mx, fdpp<0x122>(mx));   // ror:2
    mx = fmaxf(mx, fdpp<0x121>(mx));   // ror:1
    float e = __expf(lg - mx);
    float s = e;
    s += fdpp<0x128>(s);
    s += fdpp<0x124>(s);
    s += fdpp<0x122>(s);
    s += fdpp<0x121>(s);
    const float aw = e * (1.0f / s);

    const int W  = 128 >> lvl;
    const int st = (lvl == 0) ? 0 : (lvl == 1) ? 16384
                 : (lvl == 2) ? 20480 : 21504;
    const float fW = (float)W;

    const float2 rxy = *(const float2*)&refpts[qn * 8 + lvl * 2];
    unsigned oo = *(const unsigned*)(offbf + qn * 256 + m * 32 + lvl * 8 + pt * 2);
    const float ox = bf2f((unsigned short)(oo & 0xffff));
    const float oy = bf2f((unsigned short)(oo >> 16));

    const float x = fmaf(rxy.x, fW, ox) - 0.5f;
    const float y = fmaf(rxy.y, fW, oy) - 0.5f;
    const float x0f = floorf(x), y0f = floorf(y);
    const float fx = x - x0f, fy = y - y0f;
    const int xi = (int)x0f + cx;
    const int yi = (int)y0f + cy;
    const float wx = cx ? fx : (1.0f - fx);
    const float wy = cy ? fy : (1.0f - fy);
    const bool ok = (xi >= 0) & (xi <= W - 1) & (yi >= 0) & (yi <= W - 1);
    const float wt = ok ? aw * wx * wy : 0.0f;
    const int xc = min(max(xi, 0), W - 1);
    const int yc = min(max(yi, 0), W - 1);
    const int addr = n * 21760 + st + yc * W + xc;          // < 43520

    const unsigned short wh = __builtin_bit_cast(unsigned short, (_Float16)wt);
    const unsigned meta = ((unsigned)addr << 16) | (unsigned)wh;

    // store meta by corner id = p*4 + c
    meta_lds[wid][(lane & 15) * 4 + (lane >> 4)] = meta;
    asm volatile("s_waitcnt lgkmcnt(0)" ::: "memory");

    // ---------------- consumer: lane = q4 + 4*cslot ----------------
    const int q4    = lane & 3;             // 16B quarter of the 64B line
    const int cslot = lane >> 2;            // 16 corner slots

    unsigned pm[4];
#pragma unroll
    for (int it = 0; it < 4; ++it)
        pm[it] = meta_lds[wid][it * 16 + cslot];

    const uint4* vb = (const uint4*)((const char*)valuef16 + m * 64 + q4 * 16);

    uint4 vv[4];
#pragma unroll
    for (int it = 0; it < 4; ++it)
        vv[it] = vb[(size_t)(pm[it] >> 16) * 32];   // pixel*512B / 16

    float a[8] = {};
#pragma unroll
    for (int it = 0; it < 4; ++it) {
        const float w = f16lo(pm[it]);
        a[0] = fmaf(f16lo(vv[it].x), w, a[0]);
        a[1] = fmaf(f16hi(vv[it].x), w, a[1]);
        a[2] = fmaf(f16lo(vv[it].y), w, a[2]);
        a[3] = fmaf(f16hi(vv[it].y), w, a[3]);
        a[4] = fmaf(f16lo(vv[it].z), w, a[4]);
        a[5] = fmaf(f16hi(vv[it].z), w, a[5]);
        a[6] = fmaf(f16lo(vv[it].w), w, a[6]);
        a[7] = fmaf(f16hi(vv[it].w), w, a[7]);
    }

    // fold cslot bits 0,1 (lane^4, lane^8) on the VALU pipe (within 16-row)
#pragma unroll
    for (int j = 0; j < 8; ++j) a[j] += fdpp<0x124>(a[j]);   // ror:4
#pragma unroll
    for (int j = 0; j < 8; ++j) a[j] += fdpp<0x128>(a[j]);   // ror:8

    // fold cslot bits 2,3 (lane^16, lane^32) via LDS partial exchange
    *(float4*)&part[wid][lane][0] = make_float4(a[0], a[1], a[2], a[3]);
    *(float4*)&part[wid][lane][4] = make_float4(a[4], a[5], a[6], a[7]);
    asm volatile("s_waitcnt lgkmcnt(0)" ::: "memory");
    float4 p10 = *(const float4*)&part[wid][lane ^ 16][0];
    float4 p11 = *(const float4*)&part[wid][lane ^ 16][4];
    float4 p20 = *(const float4*)&part[wid][lane ^ 32][0];
    float4 p21 = *(const float4*)&part[wid][lane ^ 32][4];
    float4 p30 = *(const float4*)&part[wid][lane ^ 48][0];
    float4 p31 = *(const float4*)&part[wid][lane ^ 48][4];
    a[0] += p10.x + p20.x + p30.x;
    a[1] += p10.y + p20.y + p30.y;
    a[2] += p10.z + p20.z + p30.z;
    a[3] += p10.w + p20.w + p30.w;
    a[4] += p11.x + p21.x + p31.x;
    a[5] += p11.y + p21.y + p31.y;
    a[6] += p11.z + p21.z + p31.z;
    a[7] += p11.w + p21.w + p31.w;

    if (lane < 4) {
        uint4 o;
        o.x = ((unsigned)f2bf(a[1]) << 16) | f2bf(a[0]);
        o.y = ((unsigned)f2bf(a[3]) << 16) | f2bf(a[2]);
        o.z = ((unsigned)f2bf(a[5]) << 16) | f2bf(a[4]);
        o.w = ((unsigned)f2bf(a[7]) << 16) | f2bf(a[6]);
        *(uint4*)(accbf + (long)qn * 256 + m * 32 + q4 * 8) = o;
    }
}

// ---------------------------------------------------------------------------
// fp32 fallback kernels (used only if workspace is too small)
// ---------------------------------------------------------------------------
__global__ __launch_bounds__(256) void gemm_k256(
    const float* __restrict__ A, const float* __restrict__ B,
    const float* __restrict__ bias, float* __restrict__ C,
    int M, int N)
{
    __shared__ float As[16][68];
    __shared__ float Bs[16][68];

    const int tid = threadIdx.x;
    const int tx = tid & 15, ty = tid >> 4;
    const int bx = blockIdx.x, by = blockIdx.y;

    const int arow = tid >> 2;
    const int ak   = (tid & 3) << 2;
    const int bk   = tid >> 4;
    const int bcol = (tid & 15) << 2;

    const float* Ag = A + (long)(by * 64 + arow) * 256 + ak;
    const float* Bg = B + (long)bk * N + bx * 64 + bcol;

    float acc[4][4] = {};

    for (int k0 = 0; k0 < 256; k0 += 16) {
        float4 av = *(const float4*)(Ag + k0);
        float4 bv = *(const float4*)(Bg + (long)k0 * N);
        As[ak + 0][arow] = av.x;
        As[ak + 1][arow] = av.y;
        As[ak + 2][arow] = av.z;
        As[ak + 3][arow] = av.w;
        *(float4*)&Bs[bk][bcol] = bv;
        __syncthreads();
#pragma unroll
        for (int k = 0; k < 16; ++k) {
            float4 a4 = *(const float4*)&As[k][ty * 4];
            float4 b4 = *(const float4*)&Bs[k][tx * 4];
            float a[4] = {a4.x, a4.y, a4.z, a4.w};
            float bb[4] = {b4.x, b4.y, b4.z, b4.w};
#pragma unroll
            for (int i = 0; i < 4; ++i)
#pragma unroll
                for (int j = 0; j < 4; ++j)
                    acc[i][j] = fmaf(a[i], bb[j], acc[i][j]);
        }
        __syncthreads();
    }

    float4 b4 = *(const float4*)&bias[bx * 64 + tx * 4];
#pragma unroll
    for (int i = 0; i < 4; ++i) {
        float4 o;
        o.x = acc[i][0] + b4.x;
        o.y = acc[i][1] + b4.y;
        o.z = acc[i][2] + b4.z;
        o.w = acc[i][3] + b4.w;
        *(float4*)&C[(long)(by * 64 + ty * 4 + i) * N + bx * 64 + tx * 4] = o;
    }
}

__global__ __launch_bounds__(256) void ms_sample_f32(
    const float* __restrict__ value,
    const float* __restrict__ offraw,
    const float* __restrict__ attnraw,
    const float* __restrict__ refpts,
    float* __restrict__ acc_out)
{
    const int lane = threadIdx.x & 63;
    const int wid  = threadIdx.x >> 6;
    const long t   = (long)blockIdx.x * 4 + wid;

    const int  m  = (int)(t & 7);
    const long qn = t >> 3;

    const int p   = lane >> 2;
    const int c   = lane & 3;
    const int cx  = c & 1, cy = c >> 1;
    const int lvl = p >> 2;
    const int pt  = p & 3;

    float lg = attnraw[qn * 128 + m * 16 + p];
    float mx = lg;
    mx = fmaxf(mx, __shfl_xor(mx, 4));
    mx = fmaxf(mx, __shfl_xor(mx, 8));
    mx = fmaxf(mx, __shfl_xor(mx, 16));
    mx = fmaxf(mx, __shfl_xor(mx, 32));
    float e = __expf(lg - mx);
    float s = e;
    s += __shfl_xor(s, 4);
    s += __shfl_xor(s, 8);
    s += __shfl_xor(s, 16);
    s += __shfl_xor(s, 32);
    const float aw = e * (1.0f / s);

    const int W  = 128 >> lvl;
    const int st = (lvl == 0) ? 0 : (lvl == 1) ? 16384
                 : (lvl == 2) ? 20480 : 21504;
    const float fW = (float)W;

    const float2 rxy = *(const float2*)&refpts[qn * 8 + lvl * 2];
    float2 o2 = *(const float2*)(offraw + qn * 256 + m * 32 + lvl * 8 + pt * 2);

    const float x = fmaf(rxy.x, fW, o2.x) - 0.5f;
    const float y = fmaf(rxy.y, fW, o2.y) - 0.5f;
    const float x0f = floorf(x), y0f = floorf(y);
    const float fx = x - x0f, fy = y - y0f;
    const int xi = (int)x0f + cx;
    const int yi = (int)y0f + cy;
    const float wx = cx ? fx : (1.0f - fx);
    const float wy = cy ? fy : (1.0f - fy);
    const bool ok = (xi >= 0) & (xi <= W - 1) & (yi >= 0) & (yi <= W - 1);
    const float wt = ok ? aw * wx * wy : 0.0f;
    const int xc = min(max(xi, 0), W - 1);
    const int yc = min(max(yi, 0), W - 1);
    const int addr = st + yc * W + xc;

    const int cg   = lane & 7;
    const int slot = lane >> 3;

    const long nn = qn / LQ;
    const float4* v4 = (const float4*)(value + (nn * (long)LQ) * 256 + m * 32);

    float4 acc = make_float4(0.f, 0.f, 0.f, 0.f);
#pragma unroll
    for (int it = 0; it < 8; ++it) {
        const int src = 8 * it + slot;
        const int   a = __shfl(addr, src);
        const float w = __shfl(wt, src);
        const float4 v = v4[(long)a * 64 + cg];
        acc.x = fmaf(w, v.x, acc.x);
        acc.y = fmaf(w, v.y, acc.y);
        acc.z = fmaf(w, v.z, acc.z);
        acc.w = fmaf(w, v.w, acc.w);
    }

#pragma unroll
    for (int mask = 8; mask <= 32; mask <<= 1) {
        acc.x += __shfl_xor(acc.x, mask);
        acc.y += __shfl_xor(acc.y, mask);
        acc.z += __shfl_xor(acc.z, mask);
        acc.w += __shfl_xor(acc.w, mask);
    }

    if (lane < 8)
        *(float4*)(acc_out + qn * 256 + m * 32 + cg * 4) = acc;
}

__global__ __launch_bounds__(256) void outproj_inplace(
    float* __restrict__ io, const float* __restrict__ W,
    const float* __restrict__ bias)
{
    __shared__ float As[32][260];
    __shared__ float Bs[16][260];

    const int tid = threadIdx.x;
    const long rbase = (long)blockIdx.x * 32;

#pragma unroll
    for (int i = 0; i < 8; ++i) {
        int f4 = i * 256 + tid;
        int r  = f4 >> 6;
        int c4 = (f4 & 63) << 2;
        float4 v = *(const float4*)&io[(rbase + r) * 256 + c4];
        *(float4*)&As[r][c4] = v;
    }
    __syncthreads();

    const int tx = tid & 15, ty = tid >> 4;
    float acc[2][16] = {};

    for (int k0 = 0; k0 < 256; k0 += 16) {
#pragma unroll
        for (int i = 0; i < 4; ++i) {
            int f4 = i * 256 + tid;
            int kr = f4 >> 6;
            int c4 = (f4 & 63) << 2;
            float4 v = *(const float4*)&W[(long)(k0 + kr) * 256 + c4];
            *(float4*)&Bs[kr][c4] = v;
        }
        __syncthreads();
#pragma unroll
        for (int k = 0; k < 16; ++k) {
            float a0 = As[ty * 2 + 0][k0 + k];
            float a1 = As[ty * 2 + 1][k0 + k];
#pragma unroll
            for (int jj = 0; jj < 4; ++jj) {
                float4 b = *(const float4*)&Bs[k][tx * 4 + jj * 64];
                acc[0][jj * 4 + 0] = fmaf(a0, b.x, acc[0][jj * 4 + 0]);
                acc[0][jj * 4 + 1] = fmaf(a0, b.y, acc[0][jj * 4 + 1]);
                acc[0][jj * 4 + 2] = fmaf(a0, b.z, acc[0][jj * 4 + 2]);
                acc[0][jj * 4 + 3] = fmaf(a0, b.w, acc[0][jj * 4 + 3]);
                acc[1][jj * 4 + 0] = fmaf(a1, b.x, acc[1][jj * 4 + 0]);
                acc[1][jj * 4 + 1] = fmaf(a1, b.y, acc[1][jj * 4 + 1]);
                acc[1][jj * 4 + 2] = fmaf(a1, b.z, acc[1][jj * 4 + 2]);
                acc[1][jj * 4 + 3] = fmaf(a1, b.w, acc[1][jj * 4 + 3]);
            }
        }
        __syncthreads();
    }

#pragma unroll
    for (int i = 0; i < 2; ++i)
#pragma unroll
        for (int jj = 0; jj < 4; ++jj) {
            float4 b = *(const float4*)&bias[tx * 4 + jj * 64];
            float4 o;
            o.x = acc[i][jj * 4 + 0] + b.x;
            o.y = acc[i][jj * 4 + 1] + b.y;
            o.z = acc[i][jj * 4 + 2] + b.z;
            o.w = acc[i][jj * 4 + 3] + b.w;
            *(float4*)&io[(rbase + ty * 2 + i) * 256 + tx * 4 + jj * 64] = o;
        }
}

// ---------------------------------------------------------------------------
extern "C" void kernel_launch(void* const* d_in, const int* in_sizes, int n_in,
                              void* d_out, int out_size, void* d_ws, size_t ws_size,
                              hipStream_t stream)
{
    const float* query         = (const float*)d_in[0];
    const float* refpts        = (const float*)d_in[1];
    const float* input_flatten = (const float*)d_in[2];
    const float* W_off         = (const float*)d_in[3];
    const float* b_off         = (const float*)d_in[4];
    const float* W_attn        = (const float*)d_in[5];
    const float* b_attn        = (const float*)d_in[6];
    const float* W_val         = (const float*)d_in[7];
    const float* b_val         = (const float*)d_in[8];
    const float* W_out         = (const float*)d_in[9];
    const float* b_out         = (const float*)d_in[10];
    float* out = (float*)d_out;

    dim3 blk(256);

    const size_t NEED_BF = 78446592ULL;
    if (ws_size >= NEED_BF) {
        // -------- bf16/f16 MFMA path --------
        char* w = (char*)d_ws;
        unsigned short* valuef16 = (unsigned short*)w;               // 22,282,240
        unsigned short* offbf    = (unsigned short*)(w + 22282240);  // 22,282,240
        unsigned short* attnbf   = (unsigned short*)(w + 44564480);  // 11,141,120
        unsigned short* accbf    = (unsigned short*)(w + 55705600);  // 22,282,240
        short*          Wtv      = (short*)(w + 77987840);           // 131,072
        short*          Wcat     = (short*)(w + 78118912);           // 196,608
        short*          Wtu      = (short*)(w + 78315520);           // 131,072

        cvt_wall<<<dim3(896), blk, 0, stream>>>(
            W_val, W_off, W_attn, W_out, Wtv, Wcat, Wtu);

        gemm_mfma<1, 2><<<dim3(2, MROWS / 128), blk, 0, stream>>>(
            input_flatten, Wtv, b_val, nullptr, valuef16, nullptr, 256);
        gemm_mfma<1, 3><<<dim3(3, MROWS / 128), blk, 0, stream>>>(
            query, Wcat, b_off, b_attn, offbf, attnbf, 384);

        ms_sample_f16v<<<dim3(MROWS / 4 * 8), blk, 0, stream>>>(
            valuef16, offbf, attnbf, refpts, accbf);

        gemm_mfma<0, 0><<<dim3(2, MROWS / 128), blk, 0, stream>>>(
            accbf, Wtu, b_out, nullptr, out, nullptr, 256);
    } else {
        // -------- fp32 fallback path --------
        float* ws = (float*)d_ws;
        float* value   = ws;
        float* offraw  = value  + (long)MROWS * 256;
        float* attnraw = offraw + (long)MROWS * 256;
        float* accbuf  = attnraw + (long)MROWS * 128;

        const size_t need_with_acc =
            ((size_t)MROWS * 256 * 3 + (size_t)MROWS * 128) * sizeof(float);
        const bool has_acc = ws_size >= need_with_acc;

        gemm_k256<<<dim3(4, MROWS / 64), blk, 0, stream>>>(input_flatten, W_val, b_val, value, MROWS, 256);
        gemm_k256<<<dim3(4, MROWS / 64), blk, 0, stream>>>(query, W_off, b_off, offraw, MROWS, 256);
        gemm_k256<<<dim3(2, MROWS / 64), blk, 0, stream>>>(query, W_attn, b_attn, attnraw, MROWS, 128);

        float* accp = has_acc ? accbuf : out;
        ms_sample_f32<<<dim3((NBATCH * LQ * 8) / 4), blk, 0, stream>>>(
            value, offraw, attnraw, refpts, accp);

        if (has_acc)
            gemm_k256<<<dim3(4, MROWS / 64), blk, 0, stream>>>(accbuf, W_out, b_out, out, MROWS, 256);
        else
            outproj_inplace<<<dim3(MROWS / 32), blk, 0, stream>>>(out, W_out, b_out);
    }
}

// Round 10
// 190.762 us; speedup vs baseline: 1.0793x; 1.0793x over previous
//
#include <hip/hip_runtime.h>

#define LQ     21760
#define NBATCH 2
#define MROWS  (NBATCH * LQ)   // 43520 rows for all GEMMs

typedef __attribute__((ext_vector_type(8))) short bf16x8;
typedef __attribute__((ext_vector_type(4))) float f32x4;

__device__ __forceinline__ unsigned short f2bf(float f) {
    unsigned u = __builtin_bit_cast(unsigned, f);
    return (unsigned short)((u + 0x7fffu + ((u >> 16) & 1u)) >> 16);  // RNE
}
__device__ __forceinline__ float bf2f(unsigned short h) {
    return __builtin_bit_cast(float, (unsigned)h << 16);
}
__device__ __forceinline__ float f16lo(unsigned u) {
    return (float)__builtin_bit_cast(_Float16, (unsigned short)(u & 0xffffu));
}
__device__ __forceinline__ float f16hi(unsigned u) {
    return (float)__builtin_bit_cast(_Float16, (unsigned short)(u >> 16));
}

// DPP row-rotate (within 16-lane rows) on the VALU pipe — no DS traffic.
template <int CTRL>
__device__ __forceinline__ float fdpp(float v) {
    int r = __builtin_amdgcn_update_dpp(
        0, __builtin_bit_cast(int, v), CTRL, 0xf, 0xf, false);
    return __builtin_bit_cast(float, r);
}

// ---------------------------------------------------------------------------
// All four weight matrices: W[256][N] fp32 -> Wt[N][256] bf16, one launch.
// ---------------------------------------------------------------------------
__global__ __launch_bounds__(256) void cvt_wall(
    const float* __restrict__ Wv, const float* __restrict__ Wo,
    const float* __restrict__ Wa, const float* __restrict__ Wu,
    short* __restrict__ Wtv, short* __restrict__ Wcat, short* __restrict__ Wtu)
{
    int idx = blockIdx.x * 256 + threadIdx.x;
    if (idx < 65536) {
        int nn = idx >> 8, k = idx & 255;
        Wtv[idx] = (short)f2bf(Wv[k * 256 + nn]);
    } else if (idx < 131072) {
        int j = idx - 65536; int nn = j >> 8, k = j & 255;
        Wcat[j] = (short)f2bf(Wo[k * 256 + nn]);
    } else if (idx < 163840) {
        int j = idx - 131072; int nn = j >> 8, k = j & 255;
        Wcat[65536 + j] = (short)f2bf(Wa[k * 128 + nn]);
    } else if (idx < 229376) {
        int j = idx - 163840; int nn = j >> 8, k = j & 255;
        Wtu[j] = (short)f2bf(Wu[k * 256 + nn]);
    }
}

// ---------------------------------------------------------------------------
// MFMA GEMM: C[M x N] = A[M x 256] * Bt[N x 256]^T + bias
// Tile 128x128, 4 waves (2x2), BK=64, K=256 fixed.
// AF32=1: A fp32, converted to bf16 during LDS staging (v_cvt_pk_bf16_f32).
// OMODE: 0 = f32 out, 1 = bf16 out, 2 = f16 out, 3 = split off/attn (N=384),
//        4 = f16 head-major value layout (head, pixel, 32ch).
// ---------------------------------------------------------------------------
template <int AF32, int OMODE>
__global__ __launch_bounds__(256) void gemm_mfma(
    const void* __restrict__ Aptr,
    const short* __restrict__ Bt,
    const float* __restrict__ bias,
    const float* __restrict__ bias2,
    void* __restrict__ Cout,
    void* __restrict__ Cout2,
    int N)
{
    __shared__ short Al[128 * 64];
    __shared__ short Bl[128 * 64];

    const int tid  = threadIdx.x;
    const int lane = tid & 63, wid = tid >> 6;
    const int wr = wid >> 1, wc = wid & 1;
    const int bx = blockIdx.x, by = blockIdx.y;

    const long arow0 = (long)by * 128;
    const int  brow0 = bx * 128;

    const short* Abf = (const short*)Aptr;
    const float* Af  = (const float*)Aptr;

    f32x4 acc[4][4];
#pragma unroll
    for (int i = 0; i < 4; ++i)
#pragma unroll
        for (int j = 0; j < 4; ++j) acc[i][j] = (f32x4)0.f;

    bf16x8 ra[4], rb[4];
    float4 raf[4][2];

#pragma unroll
    for (int i = 0; i < 4; ++i) {
        int id = tid + i * 256, r = id >> 3, c = id & 7;
        if (AF32) {
            raf[i][0] = *(const float4*)(Af + (arow0 + r) * 256 + c * 8);
            raf[i][1] = *(const float4*)(Af + (arow0 + r) * 256 + c * 8 + 4);
        } else {
            ra[i] = *(const bf16x8*)(Abf + (arow0 + r) * 256 + c * 8);
        }
        rb[i] = *(const bf16x8*)(Bt + (long)(brow0 + r) * 256 + c * 8);
    }

    for (int step = 0; step < 4; ++step) {
#pragma unroll
        for (int i = 0; i < 4; ++i) {
            int id = tid + i * 256, r = id >> 3, c = id & 7;
            bf16x8 av;
            if (AF32) {
                unsigned q0, q1, q2, q3;
                asm("v_cvt_pk_bf16_f32 %0, %1, %2" : "=v"(q0) : "v"(raf[i][0].x), "v"(raf[i][0].y));
                asm("v_cvt_pk_bf16_f32 %0, %1, %2" : "=v"(q1) : "v"(raf[i][0].z), "v"(raf[i][0].w));
                asm("v_cvt_pk_bf16_f32 %0, %1, %2" : "=v"(q2) : "v"(raf[i][1].x), "v"(raf[i][1].y));
                asm("v_cvt_pk_bf16_f32 %0, %1, %2" : "=v"(q3) : "v"(raf[i][1].z), "v"(raf[i][1].w));
                uint4 u = make_uint4(q0, q1, q2, q3);
                av = __builtin_bit_cast(bf16x8, u);
            } else {
                av = ra[i];
            }
            *(bf16x8*)(Al + r * 64 + ((c ^ (r & 7)) * 8)) = av;
            *(bf16x8*)(Bl + r * 64 + ((c ^ (r & 7)) * 8)) = rb[i];
        }
        __syncthreads();
        if (step < 3) {
            const int k0 = (step + 1) * 64;
#pragma unroll
            for (int i = 0; i < 4; ++i) {
                int id = tid + i * 256, r = id >> 3, c = id & 7;
                if (AF32) {
                    raf[i][0] = *(const float4*)(Af + (arow0 + r) * 256 + k0 + c * 8);
                    raf[i][1] = *(const float4*)(Af + (arow0 + r) * 256 + k0 + c * 8 + 4);
                } else {
                    ra[i] = *(const bf16x8*)(Abf + (arow0 + r) * 256 + k0 + c * 8);
                }
                rb[i] = *(const bf16x8*)(Bt + (long)(brow0 + r) * 256 + k0 + c * 8);
            }
        }
#pragma unroll
        for (int kk = 0; kk < 2; ++kk) {
            const int g = lane >> 4;
            const int chunk = kk * 4 + g;
            bf16x8 af[4], bg[4];
#pragma unroll
            for (int mi = 0; mi < 4; ++mi) {
                int r = wr * 64 + mi * 16 + (lane & 15);
                af[mi] = *(const bf16x8*)(Al + r * 64 + ((chunk ^ (r & 7)) * 8));
            }
#pragma unroll
            for (int ni = 0; ni < 4; ++ni) {
                int r = wc * 64 + ni * 16 + (lane & 15);
                bg[ni] = *(const bf16x8*)(Bl + r * 64 + ((chunk ^ (r & 7)) * 8));
            }
#pragma unroll
            for (int mi = 0; mi < 4; ++mi)
#pragma unroll
                for (int ni = 0; ni < 4; ++ni)
                    acc[mi][ni] = __builtin_amdgcn_mfma_f32_16x16x32_bf16(
                        af[mi], bg[ni], acc[mi][ni], 0, 0, 0);
        }
        __syncthreads();
    }

#pragma unroll
    for (int mi = 0; mi < 4; ++mi) {
#pragma unroll
        for (int ni = 0; ni < 4; ++ni) {
            const int  col = bx * 128 + wc * 64 + ni * 16 + (lane & 15);
            const long row = (long)by * 128 + wr * 64 + mi * 16 + ((lane >> 4) * 4);
            float b;
            if (OMODE == 3) b = (col < 256) ? bias[col] : bias2[col - 256];
            else            b = bias[col];
#pragma unroll
            for (int q = 0; q < 4; ++q) {
                float v = acc[mi][ni][q] + b;
                if (OMODE == 0) {
                    ((float*)Cout)[(row + q) * N + col] = v;
                } else if (OMODE == 1) {
                    ((unsigned short*)Cout)[(row + q) * N + col] = f2bf(v);
                } else if (OMODE == 2) {
                    ((unsigned short*)Cout)[(row + q) * N + col] =
                        __builtin_bit_cast(unsigned short, (_Float16)v);
                } else if (OMODE == 4) {
                    const int mh = col >> 5, ch = col & 31;
                    ((unsigned short*)Cout)[((size_t)mh * MROWS + (row + q)) * 32 + ch] =
                        __builtin_bit_cast(unsigned short, (_Float16)v);
                } else {
                    if (col < 256)
                        ((unsigned short*)Cout)[(row + q) * 256 + col] = f2bf(v);
                    else
                        ((unsigned short*)Cout2)[(row + q) * 128 + (col - 256)] = f2bf(v);
                }
            }
        }
    }
}

// ---------------------------------------------------------------------------
// Fused softmax + sampling; value f16 HEAD-MAJOR (head, pixel, 32ch):
// x-adjacent corner pixels are contiguous -> one 128B span covers both
// x-corners of a (point,yrow). 32 random 128B touches per task (was 64x64B).
// Producer (lane = p + 16*c): DPP softmax; cx=0 lanes emit per-(p,row) meta
//   {base addr = clamp(x0,0,W-2), wl, wr} via the clamp-edge identity
//   wl=(x0==bx)?w0:w1, wr=(x0==bx)?w1:w0  (w0/w1 already validity-zeroed).
// Consumer (lane = cg + 8*slot): 4 x dwordx4, 8 lanes x 16B = 128B per meta.
//   cg>>2 selects L/R weight; cg&3 selects channel octet. DPP ror:8 fold,
//   40B-padded LDS partial reduce (2-way max), lanes<32 store bf16.
// ---------------------------------------------------------------------------
__global__ __launch_bounds__(256, 8) void ms_sample_f16v(
    const unsigned short* __restrict__ valuef16, // (8, 43520, 32) f16 head-major
    const unsigned short* __restrict__ offbf,    // (43520, 256) bf16
    const unsigned short* __restrict__ attnbf,   // (43520, 128) bf16
    const float* __restrict__ refpts,            // (43520, 4, 2)
    unsigned short* __restrict__ accbf)          // (43520, 256) bf16
{
    __shared__ uint2 meta_lds[4][32];     // 1 KB
    __shared__ float part[4][32][10];     // 5 KB (40B stride: b64-aligned, 2-way max)

    const int lane = threadIdx.x & 63;
    const int wid  = threadIdx.x >> 6;
    const int b    = blockIdx.x;
    const int m    = b & 7;                 // block-uniform head
    const int qn   = (b >> 3) * 4 + wid;    // 0..43519
    const int n    = (qn >= LQ) ? 1 : 0;

    // ---------------- producer: lane = p + 16*c ----------------
    const int p   = lane & 15;              // point 0..15 (within DPP row)
    const int c   = lane >> 4;              // corner 0..3: (cx,cy)=(c&1,c>>1)
    const int cx  = c & 1, cy = c >> 1;
    const int lvl = p >> 2;
    const int pt  = p & 3;

    float lg = bf2f(attnbf[qn * 128 + m * 16 + p]);

    float mx = lg;
    mx = fmaxf(mx, fdpp<0x128>(mx));   // ror:8
    mx = fmaxf(mx, fdpp<0x124>(mx));   // ror:4
    mx = fmaxf(mx, fdpp<0x122>(mx));   // ror:2
    mx = fmaxf(mx, fdpp<0x121>(mx));   // ror:1
    float e = __expf(lg - mx);
    float s = e;
    s += fdpp<0x128>(s);
    s += fdpp<0x124>(s);
    s += fdpp<0x122>(s);
    s += fdpp<0x121>(s);
    const float aw = e * (1.0f / s);

    const int W  = 128 >> lvl;
    const int st = (lvl == 0) ? 0 : (lvl == 1) ? 16384
                 : (lvl == 2) ? 20480 : 21504;
    const float fW = (float)W;

    const float2 rxy = *(const float2*)&refpts[qn * 8 + lvl * 2];
    unsigned oo = *(const unsigned*)(offbf + qn * 256 + m * 32 + lvl * 8 + pt * 2);
    const float ox = bf2f((unsigned short)(oo & 0xffff));
    const float oy = bf2f((unsigned short)(oo >> 16));

    const float x = fmaf(rxy.x, fW, ox) - 0.5f;
    const float y = fmaf(rxy.y, fW, oy) - 0.5f;
    const float x0f = floorf(x), y0f = floorf(y);
    const float fx = x - x0f, fy = y - y0f;
    const int x0i = (int)x0f;
    const int xi = x0i + cx;
    const int yi = (int)y0f + cy;
    const float wx = cx ? fx : (1.0f - fx);
    const float wy = cy ? fy : (1.0f - fy);
    const bool ok = (xi >= 0) & (xi <= W - 1) & (yi >= 0) & (yi <= W - 1);
    const float wt = ok ? aw * wx * wy : 0.0f;   // validity-zeroed corner weight
    const int yc = min(max(yi, 0), W - 1);

    // partner corner's weight (cx=1, same p, same cy) lives at lane+16
    const float w1 = __shfl(wt, lane + 16);

    if (cx == 0) {
        const int bxp = min(max(x0i, 0), W - 2);
        const float wl = (x0i == bxp) ? wt : w1;
        const float wr = (x0i == bxp) ? w1 : wt;
        const int addr = n * 21760 + st + yc * W + bxp;   // base pixel (17 bits)
        const unsigned wp =
            (unsigned)__builtin_bit_cast(unsigned short, (_Float16)wl) |
            ((unsigned)__builtin_bit_cast(unsigned short, (_Float16)wr) << 16);
        meta_lds[wid][p * 2 + cy] = make_uint2((unsigned)addr, wp);
    }
    asm volatile("s_waitcnt lgkmcnt(0)" ::: "memory");

    // ---------------- consumer: lane = cg + 8*slot ----------------
    const int cg   = lane & 7;
    const int slot = lane >> 3;

    uint2 mt[4];
#pragma unroll
    for (int it = 0; it < 4; ++it)
        mt[it] = meta_lds[wid][it * 8 + slot];

    const char* vbh = (const char*)(valuef16 + (size_t)m * MROWS * 32);
    const unsigned mc = (unsigned)(cg * 16);

    uint4 vv[4];
#pragma unroll
    for (int it = 0; it < 4; ++it)
        vv[it] = *(const uint4*)(vbh + (((size_t)mt[it].x) << 6) + mc);

    const int wsh = (cg >> 2) << 4;     // 0 for pixel-L lanes, 16 for pixel-R
    float a[8] = {};
#pragma unroll
    for (int it = 0; it < 4; ++it) {
        const float w = (float)__builtin_bit_cast(
            _Float16, (unsigned short)((mt[it].y >> wsh) & 0xffffu));
        a[0] = fmaf(f16lo(vv[it].x), w, a[0]);
        a[1] = fmaf(f16hi(vv[it].x), w, a[1]);
        a[2] = fmaf(f16lo(vv[it].y), w, a[2]);
        a[3] = fmaf(f16hi(vv[it].y), w, a[3]);
        a[4] = fmaf(f16lo(vv[it].z), w, a[4]);
        a[5] = fmaf(f16hi(vv[it].z), w, a[5]);
        a[6] = fmaf(f16lo(vv[it].w), w, a[6]);
        a[7] = fmaf(f16hi(vv[it].w), w, a[7]);
    }

    // fold slot parity (lane^8 within 16-row) on the VALU pipe
#pragma unroll
    for (int jj = 0; jj < 8; ++jj) a[jj] += fdpp<0x128>(a[jj]);

    // slot-even lanes write partials: idx = (lane>>4)*8 + cg, 40B stride
    if ((lane & 8) == 0) {
        float* pp = &part[wid][(lane >> 4) * 8 + cg][0];
        *(float2*)&pp[0] = make_float2(a[0], a[1]);
        *(float2*)&pp[2] = make_float2(a[2], a[3]);
        *(float2*)&pp[4] = make_float2(a[4], a[5]);
        *(float2*)&pp[6] = make_float2(a[6], a[7]);
    }
    asm volatile("s_waitcnt lgkmcnt(0)" ::: "memory");

    if (lane < 32) {
        const int o = lane >> 3, k = lane & 7;   // ch = o*8 + k = lane
        float sum = 0.f;
#pragma unroll
        for (int sp = 0; sp < 4; ++sp)
            sum += part[wid][sp * 8 + o][k] + part[wid][sp * 8 + o + 4][k];
        accbf[(size_t)qn * 256 + m * 32 + lane] = f2bf(sum);
    }
}

// ---------------------------------------------------------------------------
// fp32 fallback kernels (used only if workspace is too small)
// ---------------------------------------------------------------------------
__global__ __launch_bounds__(256) void gemm_k256(
    const float* __restrict__ A, const float* __restrict__ B,
    const float* __restrict__ bias, float* __restrict__ C,
    int M, int N)
{
    __shared__ float As[16][68];
    __shared__ float Bs[16][68];

    const int tid = threadIdx.x;
    const int tx = tid & 15, ty = tid >> 4;
    const int bx = blockIdx.x, by = blockIdx.y;

    const int arow = tid >> 2;
    const int ak   = (tid & 3) << 2;
    const int bk   = tid >> 4;
    const int bcol = (tid & 15) << 2;

    const float* Ag = A + (long)(by * 64 + arow) * 256 + ak;
    const float* Bg = B + (long)bk * N + bx * 64 + bcol;

    float acc[4][4] = {};

    for (int k0 = 0; k0 < 256; k0 += 16) {
        float4 av = *(const float4*)(Ag + k0);
        float4 bv = *(const float4*)(Bg + (long)k0 * N);
        As[ak + 0][arow] = av.x;
        As[ak + 1][arow] = av.y;
        As[ak + 2][arow] = av.z;
        As[ak + 3][arow] = av.w;
        *(float4*)&Bs[bk][bcol] = bv;
        __syncthreads();
#pragma unroll
        for (int k = 0; k < 16; ++k) {
            float4 a4 = *(const float4*)&As[k][ty * 4];
            float4 b4 = *(const float4*)&Bs[k][tx * 4];
            float a[4] = {a4.x, a4.y, a4.z, a4.w};
            float bb[4] = {b4.x, b4.y, b4.z, b4.w};
#pragma unroll
            for (int i = 0; i < 4; ++i)
#pragma unroll
                for (int j = 0; j < 4; ++j)
                    acc[i][j] = fmaf(a[i], bb[j], acc[i][j]);
        }
        __syncthreads();
    }

    float4 b4 = *(const float4*)&bias[bx * 64 + tx * 4];
#pragma unroll
    for (int i = 0; i < 4; ++i) {
        float4 o;
        o.x = acc[i][0] + b4.x;
        o.y = acc[i][1] + b4.y;
        o.z = acc[i][2] + b4.z;
        o.w = acc[i][3] + b4.w;
        *(float4*)&C[(long)(by * 64 + ty * 4 + i) * N + bx * 64 + tx * 4] = o;
    }
}

__global__ __launch_bounds__(256) void ms_sample_f32(
    const float* __restrict__ value,
    const float* __restrict__ offraw,
    const float* __restrict__ attnraw,
    const float* __restrict__ refpts,
    float* __restrict__ acc_out)
{
    const int lane = threadIdx.x & 63;
    const int wid  = threadIdx.x >> 6;
    const long t   = (long)blockIdx.x * 4 + wid;

    const int  m  = (int)(t & 7);
    const long qn = t >> 3;

    const int p   = lane >> 2;
    const int c   = lane & 3;
    const int cx  = c & 1, cy = c >> 1;
    const int lvl = p >> 2;
    const int pt  = p & 3;

    float lg = attnraw[qn * 128 + m * 16 + p];
    float mx = lg;
    mx = fmaxf(mx, __shfl_xor(mx, 4));
    mx = fmaxf(mx, __shfl_xor(mx, 8));
    mx = fmaxf(mx, __shfl_xor(mx, 16));
    mx = fmaxf(mx, __shfl_xor(mx, 32));
    float e = __expf(lg - mx);
    float s = e;
    s += __shfl_xor(s, 4);
    s += __shfl_xor(s, 8);
    s += __shfl_xor(s, 16);
    s += __shfl_xor(s, 32);
    const float aw = e * (1.0f / s);

    const int W  = 128 >> lvl;
    const int st = (lvl == 0) ? 0 : (lvl == 1) ? 16384
                 : (lvl == 2) ? 20480 : 21504;
    const float fW = (float)W;

    const float2 rxy = *(const float2*)&refpts[qn * 8 + lvl * 2];
    float2 o2 = *(const float2*)(offraw + qn * 256 + m * 32 + lvl * 8 + pt * 2);

    const float x = fmaf(rxy.x, fW, o2.x) - 0.5f;
    const float y = fmaf(rxy.y, fW, o2.y) - 0.5f;
    const float x0f = floorf(x), y0f = floorf(y);
    const float fx = x - x0f, fy = y - y0f;
    const int xi = (int)x0f + cx;
    const int yi = (int)y0f + cy;
    const float wx = cx ? fx : (1.0f - fx);
    const float wy = cy ? fy : (1.0f - fy);
    const bool ok = (xi >= 0) & (xi <= W - 1) & (yi >= 0) & (yi <= W - 1);
    const float wt = ok ? aw * wx * wy : 0.0f;
    const int xc = min(max(xi, 0), W - 1);
    const int yc = min(max(yi, 0), W - 1);
    const int addr = st + yc * W + xc;

    const int cg   = lane & 7;
    const int slot = lane >> 3;

    const long nn = qn / LQ;
    const float4* v4 = (const float4*)(value + (nn * (long)LQ) * 256 + m * 32);

    float4 acc = make_float4(0.f, 0.f, 0.f, 0.f);
#pragma unroll
    for (int it = 0; it < 8; ++it) {
        const int src = 8 * it + slot;
        const int   a = __shfl(addr, src);
        const float w = __shfl(wt, src);
        const float4 v = v4[(long)a * 64 + cg];
        acc.x = fmaf(w, v.x, acc.x);
        acc.y = fmaf(w, v.y, acc.y);
        acc.z = fmaf(w, v.z, acc.z);
        acc.w = fmaf(w, v.w, acc.w);
    }

#pragma unroll
    for (int mask = 8; mask <= 32; mask <<= 1) {
        acc.x += __shfl_xor(acc.x, mask);
        acc.y += __shfl_xor(acc.y, mask);
        acc.z += __shfl_xor(acc.z, mask);
        acc.w += __shfl_xor(acc.w, mask);
    }

    if (lane < 8)
        *(float4*)(acc_out + qn * 256 + m * 32 + cg * 4) = acc;
}

__global__ __launch_bounds__(256) void outproj_inplace(
    float* __restrict__ io, const float* __restrict__ W,
    const float* __restrict__ bias)
{
    __shared__ float As[32][260];
    __shared__ float Bs[16][260];

    const int tid = threadIdx.x;
    const long rbase = (long)blockIdx.x * 32;

#pragma unroll
    for (int i = 0; i < 8; ++i) {
        int f4 = i * 256 + tid;
        int r  = f4 >> 6;
        int c4 = (f4 & 63) << 2;
        float4 v = *(const float4*)&io[(rbase + r) * 256 + c4];
        *(float4*)&As[r][c4] = v;
    }
    __syncthreads();

    const int tx = tid & 15, ty = tid >> 4;
    float acc[2][16] = {};

    for (int k0 = 0; k0 < 256; k0 += 16) {
#pragma unroll
        for (int i = 0; i < 4; ++i) {
            int f4 = i * 256 + tid;
            int kr = f4 >> 6;
            int c4 = (f4 & 63) << 2;
            float4 v = *(const float4*)&W[(long)(k0 + kr) * 256 + c4];
            *(float4*)&Bs[kr][c4] = v;
        }
        __syncthreads();
#pragma unroll
        for (int k = 0; k < 16; ++k) {
            float a0 = As[ty * 2 + 0][k0 + k];
            float a1 = As[ty * 2 + 1][k0 + k];
#pragma unroll
            for (int jj = 0; jj < 4; ++jj) {
                float4 b = *(const float4*)&Bs[k][tx * 4 + jj * 64];
                acc[0][jj * 4 + 0] = fmaf(a0, b.x, acc[0][jj * 4 + 0]);
                acc[0][jj * 4 + 1] = fmaf(a0, b.y, acc[0][jj * 4 + 1]);
                acc[0][jj * 4 + 2] = fmaf(a0, b.z, acc[0][jj * 4 + 2]);
                acc[0][jj * 4 + 3] = fmaf(a0, b.w, acc[0][jj * 4 + 3]);
                acc[1][jj * 4 + 0] = fmaf(a1, b.x, acc[1][jj * 4 + 0]);
                acc[1][jj * 4 + 1] = fmaf(a1, b.y, acc[1][jj * 4 + 1]);
                acc[1][jj * 4 + 2] = fmaf(a1, b.z, acc[1][jj * 4 + 2]);
                acc[1][jj * 4 + 3] = fmaf(a1, b.w, acc[1][jj * 4 + 3]);
            }
        }
        __syncthreads();
    }

#pragma unroll
    for (int i = 0; i < 2; ++i)
#pragma unroll
        for (int jj = 0; jj < 4; ++jj) {
            float4 b = *(const float4*)&bias[tx * 4 + jj * 64];
            float4 o;
            o.x = acc[i][jj * 4 + 0] + b.x;
            o.y = acc[i][jj * 4 + 1] + b.y;
            o.z = acc[i][jj * 4 + 2] + b.z;
            o.w = acc[i][jj * 4 + 3] + b.w;
            *(float4*)&io[(rbase + ty * 2 + i) * 256 + tx * 4 + jj * 64] = o;
        }
}

// ---------------------------------------------------------------------------
extern "C" void kernel_launch(void* const* d_in, const int* in_sizes, int n_in,
                              void* d_out, int out_size, void* d_ws, size_t ws_size,
                              hipStream_t stream)
{
    const float* query         = (const float*)d_in[0];
    const float* refpts        = (const float*)d_in[1];
    const float* input_flatten = (const float*)d_in[2];
    const float* W_off         = (const float*)d_in[3];
    const float* b_off         = (const float*)d_in[4];
    const float* W_attn        = (const float*)d_in[5];
    const float* b_attn        = (const float*)d_in[6];
    const float* W_val         = (const float*)d_in[7];
    const float* b_val         = (const float*)d_in[8];
    const float* W_out         = (const float*)d_in[9];
    const float* b_out         = (const float*)d_in[10];
    float* out = (float*)d_out;

    dim3 blk(256);

    const size_t NEED_BF = 78446592ULL;
    if (ws_size >= NEED_BF) {
        // -------- bf16/f16 MFMA path --------
        char* w = (char*)d_ws;
        unsigned short* valuef16 = (unsigned short*)w;               // 22,282,240
        unsigned short* offbf    = (unsigned short*)(w + 22282240);  // 22,282,240
        unsigned short* attnbf   = (unsigned short*)(w + 44564480);  // 11,141,120
        unsigned short* accbf    = (unsigned short*)(w + 55705600);  // 22,282,240
        short*          Wtv      = (short*)(w + 77987840);           // 131,072
        short*          Wcat     = (short*)(w + 78118912);           // 196,608
        short*          Wtu      = (short*)(w + 78315520);           // 131,072

        cvt_wall<<<dim3(896), blk, 0, stream>>>(
            W_val, W_off, W_attn, W_out, Wtv, Wcat, Wtu);

        // value in f16 head-major (head, pixel, 32ch)
        gemm_mfma<1, 4><<<dim3(2, MROWS / 128), blk, 0, stream>>>(
            input_flatten, Wtv, b_val, nullptr, valuef16, nullptr, 256);
        gemm_mfma<1, 3><<<dim3(3, MROWS / 128), blk, 0, stream>>>(
            query, Wcat, b_off, b_attn, offbf, attnbf, 384);

        ms_sample_f16v<<<dim3(MROWS / 4 * 8), blk, 0, stream>>>(
            valuef16, offbf, attnbf, refpts, accbf);

        gemm_mfma<0, 0><<<dim3(2, MROWS / 128), blk, 0, stream>>>(
            accbf, Wtu, b_out, nullptr, out, nullptr, 256);
    } else {
        // -------- fp32 fallback path --------
        float* ws = (float*)d_ws;
        float* value   = ws;
        float* offraw  = value  + (long)MROWS * 256;
        float* attnraw = offraw + (long)MROWS * 256;
        float* accbuf  = attnraw + (long)MROWS * 128;

        const size_t need_with_acc =
            ((size_t)MROWS * 256 * 3 + (size_t)MROWS * 128) * sizeof(float);
        const bool has_acc = ws_size >= need_with_acc;

        gemm_k256<<<dim3(4, MROWS / 64), blk, 0, stream>>>(input_flatten, W_val, b_val, value, MROWS, 256);
        gemm_k256<<<dim3(4, MROWS / 64), blk, 0, stream>>>(query, W_off, b_off, offraw, MROWS, 256);
        gemm_k256<<<dim3(2, MROWS / 64), blk, 0, stream>>>(query, W_attn, b_attn, attnraw, MROWS, 128);

        float* accp = has_acc ? accbuf : out;
        ms_sample_f32<<<dim3((NBATCH * LQ * 8) / 4), blk, 0, stream>>>(
            value, offraw, attnraw, refpts, accp);

        if (has_acc)
            gemm_k256<<<dim3(4, MROWS / 64), blk, 0, stream>>>(accbuf, W_out, b_out, out, MROWS, 256);
        else
            outproj_inplace<<<dim3(MROWS / 32), blk, 0, stream>>>(out, W_out, b_out);
    }
}

// Round 11
// 157.118 us; speedup vs baseline: 1.3104x; 1.2141x over previous
//
#include <hip/hip_runtime.h>

#define LQ     21760
#define NBATCH 2
#define MROWS  (NBATCH * LQ)   // 43520 rows for all GEMMs

typedef __attribute__((ext_vector_type(8))) short bf16x8;
typedef __attribute__((ext_vector_type(4))) float f32x4;

__device__ __forceinline__ unsigned short f2bf(float f) {
    unsigned u = __builtin_bit_cast(unsigned, f);
    return (unsigned short)((u + 0x7fffu + ((u >> 16) & 1u)) >> 16);  // RNE
}
__device__ __forceinline__ float bf2f(unsigned short h) {
    return __builtin_bit_cast(float, (unsigned)h << 16);
}
__device__ __forceinline__ float f16lo(unsigned u) {
    return (float)__builtin_bit_cast(_Float16, (unsigned short)(u & 0xffffu));
}
__device__ __forceinline__ float f16hi(unsigned u) {
    return (float)__builtin_bit_cast(_Float16, (unsigned short)(u >> 16));
}

// DPP row-rotate (within 16-lane rows) on the VALU pipe — no DS traffic.
template <int CTRL>
__device__ __forceinline__ float fdpp(float v) {
    int r = __builtin_amdgcn_update_dpp(
        0, __builtin_bit_cast(int, v), CTRL, 0xf, 0xf, false);
    return __builtin_bit_cast(float, r);
}

// ---------------------------------------------------------------------------
// All four weight matrices: W[256][N] fp32 -> Wt[N][256] bf16, one launch.
// ---------------------------------------------------------------------------
__global__ __launch_bounds__(256) void cvt_wall(
    const float* __restrict__ Wv, const float* __restrict__ Wo,
    const float* __restrict__ Wa, const float* __restrict__ Wu,
    short* __restrict__ Wtv, short* __restrict__ Wcat, short* __restrict__ Wtu)
{
    int idx = blockIdx.x * 256 + threadIdx.x;
    if (idx < 65536) {
        int nn = idx >> 8, k = idx & 255;
        Wtv[idx] = (short)f2bf(Wv[k * 256 + nn]);
    } else if (idx < 131072) {
        int j = idx - 65536; int nn = j >> 8, k = j & 255;
        Wcat[j] = (short)f2bf(Wo[k * 256 + nn]);
    } else if (idx < 163840) {
        int j = idx - 131072; int nn = j >> 8, k = j & 255;
        Wcat[65536 + j] = (short)f2bf(Wa[k * 128 + nn]);
    } else if (idx < 229376) {
        int j = idx - 163840; int nn = j >> 8, k = j & 255;
        Wtu[j] = (short)f2bf(Wu[k * 256 + nn]);
    }
}

// ---------------------------------------------------------------------------
// MFMA GEMM: C[M x N] = A[M x 256] * Bt[N x 256]^T + bias
// Tile 128x128, 4 waves (2x2), BK=64, K=256 fixed.
// AF32=1: A fp32, converted to bf16 during LDS staging (v_cvt_pk_bf16_f32).
// OMODE: 0 = f32 out, 1 = bf16 out, 2 = f16 out, 3 = split off/attn (N=384),
//        4 = f16 head-major value layout (head, pixel, 32ch).
// ---------------------------------------------------------------------------
template <int AF32, int OMODE>
__global__ __launch_bounds__(256) void gemm_mfma(
    const void* __restrict__ Aptr,
    const short* __restrict__ Bt,
    const float* __restrict__ bias,
    const float* __restrict__ bias2,
    void* __restrict__ Cout,
    void* __restrict__ Cout2,
    int N)
{
    __shared__ short Al[128 * 64];
    __shared__ short Bl[128 * 64];

    const int tid  = threadIdx.x;
    const int lane = tid & 63, wid = tid >> 6;
    const int wr = wid >> 1, wc = wid & 1;
    const int bx = blockIdx.x, by = blockIdx.y;

    const long arow0 = (long)by * 128;
    const int  brow0 = bx * 128;

    const short* Abf = (const short*)Aptr;
    const float* Af  = (const float*)Aptr;

    f32x4 acc[4][4];
#pragma unroll
    for (int i = 0; i < 4; ++i)
#pragma unroll
        for (int j = 0; j < 4; ++j) acc[i][j] = (f32x4)0.f;

    bf16x8 ra[4], rb[4];
    float4 raf[4][2];

#pragma unroll
    for (int i = 0; i < 4; ++i) {
        int id = tid + i * 256, r = id >> 3, c = id & 7;
        if (AF32) {
            raf[i][0] = *(const float4*)(Af + (arow0 + r) * 256 + c * 8);
            raf[i][1] = *(const float4*)(Af + (arow0 + r) * 256 + c * 8 + 4);
        } else {
            ra[i] = *(const bf16x8*)(Abf + (arow0 + r) * 256 + c * 8);
        }
        rb[i] = *(const bf16x8*)(Bt + (long)(brow0 + r) * 256 + c * 8);
    }

    for (int step = 0; step < 4; ++step) {
#pragma unroll
        for (int i = 0; i < 4; ++i) {
            int id = tid + i * 256, r = id >> 3, c = id & 7;
            bf16x8 av;
            if (AF32) {
                unsigned q0, q1, q2, q3;
                asm("v_cvt_pk_bf16_f32 %0, %1, %2" : "=v"(q0) : "v"(raf[i][0].x), "v"(raf[i][0].y));
                asm("v_cvt_pk_bf16_f32 %0, %1, %2" : "=v"(q1) : "v"(raf[i][0].z), "v"(raf[i][0].w));
                asm("v_cvt_pk_bf16_f32 %0, %1, %2" : "=v"(q2) : "v"(raf[i][1].x), "v"(raf[i][1].y));
                asm("v_cvt_pk_bf16_f32 %0, %1, %2" : "=v"(q3) : "v"(raf[i][1].z), "v"(raf[i][1].w));
                uint4 u = make_uint4(q0, q1, q2, q3);
                av = __builtin_bit_cast(bf16x8, u);
            } else {
                av = ra[i];
            }
            *(bf16x8*)(Al + r * 64 + ((c ^ (r & 7)) * 8)) = av;
            *(bf16x8*)(Bl + r * 64 + ((c ^ (r & 7)) * 8)) = rb[i];
        }
        __syncthreads();
        if (step < 3) {
            const int k0 = (step + 1) * 64;
#pragma unroll
            for (int i = 0; i < 4; ++i) {
                int id = tid + i * 256, r = id >> 3, c = id & 7;
                if (AF32) {
                    raf[i][0] = *(const float4*)(Af + (arow0 + r) * 256 + k0 + c * 8);
                    raf[i][1] = *(const float4*)(Af + (arow0 + r) * 256 + k0 + c * 8 + 4);
                } else {
                    ra[i] = *(const bf16x8*)(Abf + (arow0 + r) * 256 + k0 + c * 8);
                }
                rb[i] = *(const bf16x8*)(Bt + (long)(brow0 + r) * 256 + k0 + c * 8);
            }
        }
#pragma unroll
        for (int kk = 0; kk < 2; ++kk) {
            const int g = lane >> 4;
            const int chunk = kk * 4 + g;
            bf16x8 af[4], bg[4];
#pragma unroll
            for (int mi = 0; mi < 4; ++mi) {
                int r = wr * 64 + mi * 16 + (lane & 15);
                af[mi] = *(const bf16x8*)(Al + r * 64 + ((chunk ^ (r & 7)) * 8));
            }
#pragma unroll
            for (int ni = 0; ni < 4; ++ni) {
                int r = wc * 64 + ni * 16 + (lane & 15);
                bg[ni] = *(const bf16x8*)(Bl + r * 64 + ((chunk ^ (r & 7)) * 8));
            }
#pragma unroll
            for (int mi = 0; mi < 4; ++mi)
#pragma unroll
                for (int ni = 0; ni < 4; ++ni)
                    acc[mi][ni] = __builtin_amdgcn_mfma_f32_16x16x32_bf16(
                        af[mi], bg[ni], acc[mi][ni], 0, 0, 0);
        }
        __syncthreads();
    }

#pragma unroll
    for (int mi = 0; mi < 4; ++mi) {
#pragma unroll
        for (int ni = 0; ni < 4; ++ni) {
            const int  col = bx * 128 + wc * 64 + ni * 16 + (lane & 15);
            const long row = (long)by * 128 + wr * 64 + mi * 16 + ((lane >> 4) * 4);
            float b;
            if (OMODE == 3) b = (col < 256) ? bias[col] : bias2[col - 256];
            else            b = bias[col];
#pragma unroll
            for (int q = 0; q < 4; ++q) {
                float v = acc[mi][ni][q] + b;
                if (OMODE == 0) {
                    ((float*)Cout)[(row + q) * N + col] = v;
                } else if (OMODE == 1) {
                    ((unsigned short*)Cout)[(row + q) * N + col] = f2bf(v);
                } else if (OMODE == 2) {
                    ((unsigned short*)Cout)[(row + q) * N + col] =
                        __builtin_bit_cast(unsigned short, (_Float16)v);
                } else if (OMODE == 4) {
                    const int mh = col >> 5, ch = col & 31;
                    ((unsigned short*)Cout)[((size_t)mh * MROWS + (row + q)) * 32 + ch] =
                        __builtin_bit_cast(unsigned short, (_Float16)v);
                } else {
                    if (col < 256)
                        ((unsigned short*)Cout)[(row + q) * 256 + col] = f2bf(v);
                    else
                        ((unsigned short*)Cout2)[(row + q) * 128 + (col - 256)] = f2bf(v);
                }
            }
        }
    }
}

// ---------------------------------------------------------------------------
// Fused softmax + sampling; value f16 HEAD-MAJOR (head, pixel, 32ch).
// TWO tasks per wave; producer fully dense (no idle lanes, no shuffles):
//   lane = p(0..15) + 16*cy(0..1) + 32*th(0..1); one lane computes the whole
//   x-PAIR meta {base=clamp(x0,0,W-2), wl, wr} locally via the clamp-edge
//   identity. DPP softmax per 16-lane row (rows = (th,cy)).
// Consumer per task: 4 x dwordx4 (8 lanes x 16B = 128B span per meta),
//   DPP ror:8 fold, padded-LDS partial reduce, 64 lanes write 2 tasks.
// ---------------------------------------------------------------------------
__global__ __launch_bounds__(256, 8) void ms_sample_f16v(
    const unsigned short* __restrict__ valuef16, // (8, 43520, 32) f16 head-major
    const unsigned short* __restrict__ offbf,    // (43520, 256) bf16
    const unsigned short* __restrict__ attnbf,   // (43520, 128) bf16
    const float* __restrict__ refpts,            // (43520, 4, 2)
    unsigned short* __restrict__ accbf)          // (43520, 256) bf16
{
    __shared__ uint2 meta_lds[4][2][32];     // 2 KB
    __shared__ float part[4][2][32][10];     // 10.25 KB padded (40B stride)

    const int lane = threadIdx.x & 63;
    const int wid  = threadIdx.x >> 6;
    const int b    = blockIdx.x;
    const int m    = b & 7;                     // block-uniform head
    const int qn0w = (b >> 3) * 8 + 2 * wid;    // first qn of this wave

    // ---------------- producer: lane = p + 16*cy + 32*th ----------------
    const int p   = lane & 15;
    const int cy  = (lane >> 4) & 1;
    const int th  = lane >> 5;
    const int lvl = p >> 2;
    const int pt  = p & 3;
    const int qnl = qn0w + th;
    const int nb  = (qnl >= LQ) ? 1 : 0;

    float lg = bf2f(attnbf[(size_t)qnl * 128 + m * 16 + p]);

    // softmax over the 16 p-lanes of this row (rows are (th,cy) quarters)
    float mx = lg;
    mx = fmaxf(mx, fdpp<0x128>(mx));   // ror:8
    mx = fmaxf(mx, fdpp<0x124>(mx));   // ror:4
    mx = fmaxf(mx, fdpp<0x122>(mx));   // ror:2
    mx = fmaxf(mx, fdpp<0x121>(mx));   // ror:1
    float e = __expf(lg - mx);
    float s = e;
    s += fdpp<0x128>(s);
    s += fdpp<0x124>(s);
    s += fdpp<0x122>(s);
    s += fdpp<0x121>(s);
    const float aw = e * (1.0f / s);

    const int W  = 128 >> lvl;
    const int st = (lvl == 0) ? 0 : (lvl == 1) ? 16384
                 : (lvl == 2) ? 20480 : 21504;
    const float fW = (float)W;

    const float2 rxy = *(const float2*)&refpts[(size_t)qnl * 8 + lvl * 2];
    unsigned oo = *(const unsigned*)(offbf + (size_t)qnl * 256 + m * 32 + lvl * 8 + pt * 2);
    const float ox = bf2f((unsigned short)(oo & 0xffff));
    const float oy = bf2f((unsigned short)(oo >> 16));

    const float x = fmaf(rxy.x, fW, ox) - 0.5f;
    const float y = fmaf(rxy.y, fW, oy) - 0.5f;
    const float x0f = floorf(x), y0f = floorf(y);
    const float fx = x - x0f, fy = y - y0f;
    const int x0i = (int)x0f;
    const int yi  = (int)y0f + cy;

    const bool yok = (yi >= 0) & (yi <= W - 1);
    const float awwy = yok ? aw * (cy ? fy : (1.0f - fy)) : 0.0f;
    const int yc = min(max(yi, 0), W - 1);

    const bool x0ok = (x0i >= 0) & (x0i <= W - 1);
    const bool x1ok = (x0i + 1 >= 0) & (x0i + 1 <= W - 1);
    const float w0f = x0ok ? awwy * (1.0f - fx) : 0.0f;
    const float w1f = x1ok ? awwy * fx : 0.0f;

    const int bxp = min(max(x0i, 0), W - 2);
    const bool base_is_x0 = (x0i == bxp);
    const float wl = base_is_x0 ? w0f : w1f;
    const float wr = base_is_x0 ? w1f : w0f;
    const int addr = nb * 21760 + st + yc * W + bxp;       // base pixel index

    const unsigned wp =
        (unsigned)__builtin_bit_cast(unsigned short, (_Float16)wl) |
        ((unsigned)__builtin_bit_cast(unsigned short, (_Float16)wr) << 16);
    meta_lds[wid][th][p * 2 + cy] = make_uint2((unsigned)addr, wp);

    asm volatile("s_waitcnt lgkmcnt(0)" ::: "memory");
    __builtin_amdgcn_sched_barrier(0);

    // ---------------- consumer: lane = cg + 8*slot ----------------
    const int cg   = lane & 7;
    const int slot = lane >> 3;
    const char* vbh = (const char*)(valuef16 + (size_t)m * MROWS * 32);
    const unsigned mc = (unsigned)(cg * 16);
    const int wsh = (cg >> 2) << 4;     // 0: L-pixel weight, 16: R-pixel

    float a0[8] = {}, a1[8] = {};
#pragma unroll
    for (int t = 0; t < 2; ++t) {
        uint2 mt[4];
#pragma unroll
        for (int it = 0; it < 4; ++it)
            mt[it] = meta_lds[wid][t][it * 8 + slot];

        uint4 vv[4];
#pragma unroll
        for (int it = 0; it < 4; ++it)
            vv[it] = *(const uint4*)(vbh + (((size_t)mt[it].x) << 6) + mc);

        float* a = t ? a1 : a0;
#pragma unroll
        for (int it = 0; it < 4; ++it) {
            const float w = (float)__builtin_bit_cast(
                _Float16, (unsigned short)((mt[it].y >> wsh) & 0xffffu));
            a[0] = fmaf(f16lo(vv[it].x), w, a[0]);
            a[1] = fmaf(f16hi(vv[it].x), w, a[1]);
            a[2] = fmaf(f16lo(vv[it].y), w, a[2]);
            a[3] = fmaf(f16hi(vv[it].y), w, a[3]);
            a[4] = fmaf(f16lo(vv[it].z), w, a[4]);
            a[5] = fmaf(f16hi(vv[it].z), w, a[5]);
            a[6] = fmaf(f16lo(vv[it].w), w, a[6]);
            a[7] = fmaf(f16hi(vv[it].w), w, a[7]);
        }
    }

    // fold slot parity (lane^8 within 16-row) on the VALU pipe
#pragma unroll
    for (int jj = 0; jj < 8; ++jj) { a0[jj] += fdpp<0x128>(a0[jj]); a1[jj] += fdpp<0x128>(a1[jj]); }

    // even-slot lanes write partials: idx = grp(lane>>4)*8 + cg, 40B stride
    if ((lane & 8) == 0) {
        const int idx = (lane >> 4) * 8 + cg;
        float* pp0 = &part[wid][0][idx][0];
        float* pp1 = &part[wid][1][idx][0];
        *(float2*)&pp0[0] = make_float2(a0[0], a0[1]);
        *(float2*)&pp0[2] = make_float2(a0[2], a0[3]);
        *(float2*)&pp0[4] = make_float2(a0[4], a0[5]);
        *(float2*)&pp0[6] = make_float2(a0[6], a0[7]);
        *(float2*)&pp1[0] = make_float2(a1[0], a1[1]);
        *(float2*)&pp1[2] = make_float2(a1[2], a1[3]);
        *(float2*)&pp1[4] = make_float2(a1[4], a1[5]);
        *(float2*)&pp1[6] = make_float2(a1[6], a1[7]);
    }
    asm volatile("s_waitcnt lgkmcnt(0)" ::: "memory");
    __builtin_amdgcn_sched_barrier(0);

    // 64 lanes write both tasks: th = lane>>5, ch = lane&31
    {
        const int t  = lane >> 5;
        const int ch = lane & 31;
        const int o  = ch >> 3, k = ch & 7;
        float sum = 0.f;
#pragma unroll
        for (int grp = 0; grp < 4; ++grp)
            sum += part[wid][t][grp * 8 + o][k] + part[wid][t][grp * 8 + o + 4][k];
        accbf[(size_t)(qn0w + t) * 256 + m * 32 + ch] = f2bf(sum);
    }
}

// ---------------------------------------------------------------------------
// fp32 fallback kernels (used only if workspace is too small)
// ---------------------------------------------------------------------------
__global__ __launch_bounds__(256) void gemm_k256(
    const float* __restrict__ A, const float* __restrict__ B,
    const float* __restrict__ bias, float* __restrict__ C,
    int M, int N)
{
    __shared__ float As[16][68];
    __shared__ float Bs[16][68];

    const int tid = threadIdx.x;
    const int tx = tid & 15, ty = tid >> 4;
    const int bx = blockIdx.x, by = blockIdx.y;

    const int arow = tid >> 2;
    const int ak   = (tid & 3) << 2;
    const int bk   = tid >> 4;
    const int bcol = (tid & 15) << 2;

    const float* Ag = A + (long)(by * 64 + arow) * 256 + ak;
    const float* Bg = B + (long)bk * N + bx * 64 + bcol;

    float acc[4][4] = {};

    for (int k0 = 0; k0 < 256; k0 += 16) {
        float4 av = *(const float4*)(Ag + k0);
        float4 bv = *(const float4*)(Bg + (long)k0 * N);
        As[ak + 0][arow] = av.x;
        As[ak + 1][arow] = av.y;
        As[ak + 2][arow] = av.z;
        As[ak + 3][arow] = av.w;
        *(float4*)&Bs[bk][bcol] = bv;
        __syncthreads();
#pragma unroll
        for (int k = 0; k < 16; ++k) {
            float4 a4 = *(const float4*)&As[k][ty * 4];
            float4 b4 = *(const float4*)&Bs[k][tx * 4];
            float a[4] = {a4.x, a4.y, a4.z, a4.w};
            float bb[4] = {b4.x, b4.y, b4.z, b4.w};
#pragma unroll
            for (int i = 0; i < 4; ++i)
#pragma unroll
                for (int j = 0; j < 4; ++j)
                    acc[i][j] = fmaf(a[i], bb[j], acc[i][j]);
        }
        __syncthreads();
    }

    float4 b4 = *(const float4*)&bias[bx * 64 + tx * 4];
#pragma unroll
    for (int i = 0; i < 4; ++i) {
        float4 o;
        o.x = acc[i][0] + b4.x;
        o.y = acc[i][1] + b4.y;
        o.z = acc[i][2] + b4.z;
        o.w = acc[i][3] + b4.w;
        *(float4*)&C[(long)(by * 64 + ty * 4 + i) * N + bx * 64 + tx * 4] = o;
    }
}

__global__ __launch_bounds__(256) void ms_sample_f32(
    const float* __restrict__ value,
    const float* __restrict__ offraw,
    const float* __restrict__ attnraw,
    const float* __restrict__ refpts,
    float* __restrict__ acc_out)
{
    const int lane = threadIdx.x & 63;
    const int wid  = threadIdx.x >> 6;
    const long t   = (long)blockIdx.x * 4 + wid;

    const int  m  = (int)(t & 7);
    const long qn = t >> 3;

    const int p   = lane >> 2;
    const int c   = lane & 3;
    const int cx  = c & 1, cy = c >> 1;
    const int lvl = p >> 2;
    const int pt  = p & 3;

    float lg = attnraw[qn * 128 + m * 16 + p];
    float mx = lg;
    mx = fmaxf(mx, __shfl_xor(mx, 4));
    mx = fmaxf(mx, __shfl_xor(mx, 8));
    mx = fmaxf(mx, __shfl_xor(mx, 16));
    mx = fmaxf(mx, __shfl_xor(mx, 32));
    float e = __expf(lg - mx);
    float s = e;
    s += __shfl_xor(s, 4);
    s += __shfl_xor(s, 8);
    s += __shfl_xor(s, 16);
    s += __shfl_xor(s, 32);
    const float aw = e * (1.0f / s);

    const int W  = 128 >> lvl;
    const int st = (lvl == 0) ? 0 : (lvl == 1) ? 16384
                 : (lvl == 2) ? 20480 : 21504;
    const float fW = (float)W;

    const float2 rxy = *(const float2*)&refpts[qn * 8 + lvl * 2];
    float2 o2 = *(const float2*)(offraw + qn * 256 + m * 32 + lvl * 8 + pt * 2);

    const float x = fmaf(rxy.x, fW, o2.x) - 0.5f;
    const float y = fmaf(rxy.y, fW, o2.y) - 0.5f;
    const float x0f = floorf(x), y0f = floorf(y);
    const float fx = x - x0f, fy = y - y0f;
    const int xi = (int)x0f + cx;
    const int yi = (int)y0f + cy;
    const float wx = cx ? fx : (1.0f - fx);
    const float wy = cy ? fy : (1.0f - fy);
    const bool ok = (xi >= 0) & (xi <= W - 1) & (yi >= 0) & (yi <= W - 1);
    const float wt = ok ? aw * wx * wy : 0.0f;
    const int xc = min(max(xi, 0), W - 1);
    const int yc = min(max(yi, 0), W - 1);
    const int addr = st + yc * W + xc;

    const int cg   = lane & 7;
    const int slot = lane >> 3;

    const long nn = qn / LQ;
    const float4* v4 = (const float4*)(value + (nn * (long)LQ) * 256 + m * 32);

    float4 acc = make_float4(0.f, 0.f, 0.f, 0.f);
#pragma unroll
    for (int it = 0; it < 8; ++it) {
        const int src = 8 * it + slot;
        const int   a = __shfl(addr, src);
        const float w = __shfl(wt, src);
        const float4 v = v4[(long)a * 64 + cg];
        acc.x = fmaf(w, v.x, acc.x);
        acc.y = fmaf(w, v.y, acc.y);
        acc.z = fmaf(w, v.z, acc.z);
        acc.w = fmaf(w, v.w, acc.w);
    }

#pragma unroll
    for (int mask = 8; mask <= 32; mask <<= 1) {
        acc.x += __shfl_xor(acc.x, mask);
        acc.y += __shfl_xor(acc.y, mask);
        acc.z += __shfl_xor(acc.z, mask);
        acc.w += __shfl_xor(acc.w, mask);
    }

    if (lane < 8)
        *(float4*)(acc_out + qn * 256 + m * 32 + cg * 4) = acc;
}

__global__ __launch_bounds__(256) void outproj_inplace(
    float* __restrict__ io, const float* __restrict__ W,
    const float* __restrict__ bias)
{
    __shared__ float As[32][260];
    __shared__ float Bs[16][260];

    const int tid = threadIdx.x;
    const long rbase = (long)blockIdx.x * 32;

#pragma unroll
    for (int i = 0; i < 8; ++i) {
        int f4 = i * 256 + tid;
        int r  = f4 >> 6;
        int c4 = (f4 & 63) << 2;
        float4 v = *(const float4*)&io[(rbase + r) * 256 + c4];
        *(float4*)&As[r][c4] = v;
    }
    __syncthreads();

    const int tx = tid & 15, ty = tid >> 4;
    float acc[2][16] = {};

    for (int k0 = 0; k0 < 256; k0 += 16) {
#pragma unroll
        for (int i = 0; i < 4; ++i) {
            int f4 = i * 256 + tid;
            int kr = f4 >> 6;
            int c4 = (f4 & 63) << 2;
            float4 v = *(const float4*)&W[(long)(k0 + kr) * 256 + c4];
            *(float4*)&Bs[kr][c4] = v;
        }
        __syncthreads();
#pragma unroll
        for (int k = 0; k < 16; ++k) {
            float a0 = As[ty * 2 + 0][k0 + k];
            float a1 = As[ty * 2 + 1][k0 + k];
#pragma unroll
            for (int jj = 0; jj < 4; ++jj) {
                float4 b = *(const float4*)&Bs[k][tx * 4 + jj * 64];
                acc[0][jj * 4 + 0] = fmaf(a0, b.x, acc[0][jj * 4 + 0]);
                acc[0][jj * 4 + 1] = fmaf(a0, b.y, acc[0][jj * 4 + 1]);
                acc[0][jj * 4 + 2] = fmaf(a0, b.z, acc[0][jj * 4 + 2]);
                acc[0][jj * 4 + 3] = fmaf(a0, b.w, acc[0][jj * 4 + 3]);
                acc[1][jj * 4 + 0] = fmaf(a1, b.x, acc[1][jj * 4 + 0]);
                acc[1][jj * 4 + 1] = fmaf(a1, b.y, acc[1][jj * 4 + 1]);
                acc[1][jj * 4 + 2] = fmaf(a1, b.z, acc[1][jj * 4 + 2]);
                acc[1][jj * 4 + 3] = fmaf(a1, b.w, acc[1][jj * 4 + 3]);
            }
        }
        __syncthreads();
    }

#pragma unroll
    for (int i = 0; i < 2; ++i)
#pragma unroll
        for (int jj = 0; jj < 4; ++jj) {
            float4 b = *(const float4*)&bias[tx * 4 + jj * 64];
            float4 o;
            o.x = acc[i][jj * 4 + 0] + b.x;
            o.y = acc[i][jj * 4 + 1] + b.y;
            o.z = acc[i][jj * 4 + 2] + b.z;
            o.w = acc[i][jj * 4 + 3] + b.w;
            *(float4*)&io[(rbase + ty * 2 + i) * 256 + tx * 4 + jj * 64] = o;
        }
}

// ---------------------------------------------------------------------------
extern "C" void kernel_launch(void* const* d_in, const int* in_sizes, int n_in,
                              void* d_out, int out_size, void* d_ws, size_t ws_size,
                              hipStream_t stream)
{
    const float* query         = (const float*)d_in[0];
    const float* refpts        = (const float*)d_in[1];
    const float* input_flatten = (const float*)d_in[2];
    const float* W_off         = (const float*)d_in[3];
    const float* b_off         = (const float*)d_in[4];
    const float* W_attn        = (const float*)d_in[5];
    const float* b_attn        = (const float*)d_in[6];
    const float* W_val         = (const float*)d_in[7];
    const float* b_val         = (const float*)d_in[8];
    const float* W_out         = (const float*)d_in[9];
    const float* b_out         = (const float*)d_in[10];
    float* out = (float*)d_out;

    dim3 blk(256);

    const size_t NEED_BF = 78446592ULL;
    if (ws_size >= NEED_BF) {
        // -------- bf16/f16 MFMA path --------
        char* w = (char*)d_ws;
        unsigned short* valuef16 = (unsigned short*)w;               // 22,282,240
        unsigned short* offbf    = (unsigned short*)(w + 22282240);  // 22,282,240
        unsigned short* attnbf   = (unsigned short*)(w + 44564480);  // 11,141,120
        unsigned short* accbf    = (unsigned short*)(w + 55705600);  // 22,282,240
        short*          Wtv      = (short*)(w + 77987840);           // 131,072
        short*          Wcat     = (short*)(w + 78118912);           // 196,608
        short*          Wtu      = (short*)(w + 78315520);           // 131,072

        cvt_wall<<<dim3(896), blk, 0, stream>>>(
            W_val, W_off, W_attn, W_out, Wtv, Wcat, Wtu);

        // value in f16 head-major (head, pixel, 32ch)
        gemm_mfma<1, 4><<<dim3(2, MROWS / 128), blk, 0, stream>>>(
            input_flatten, Wtv, b_val, nullptr, valuef16, nullptr, 256);
        gemm_mfma<1, 3><<<dim3(3, MROWS / 128), blk, 0, stream>>>(
            query, Wcat, b_off, b_attn, offbf, attnbf, 384);

        // 2 tasks per wave, 8 tasks per block: grid = MROWS/8 * 8 heads
        ms_sample_f16v<<<dim3(MROWS / 8 * 8), blk, 0, stream>>>(
            valuef16, offbf, attnbf, refpts, accbf);

        gemm_mfma<0, 0><<<dim3(2, MROWS / 128), blk, 0, stream>>>(
            accbf, Wtu, b_out, nullptr, out, nullptr, 256);
    } else {
        // -------- fp32 fallback path --------
        float* ws = (float*)d_ws;
        float* value   = ws;
        float* offraw  = value  + (long)MROWS * 256;
        float* attnraw = offraw + (long)MROWS * 256;
        float* accbuf  = attnraw + (long)MROWS * 128;

        const size_t need_with_acc =
            ((size_t)MROWS * 256 * 3 + (size_t)MROWS * 128) * sizeof(float);
        const bool has_acc = ws_size >= need_with_acc;

        gemm_k256<<<dim3(4, MROWS / 64), blk, 0, stream>>>(input_flatten, W_val, b_val, value, MROWS, 256);
        gemm_k256<<<dim3(4, MROWS / 64), blk, 0, stream>>>(query, W_off, b_off, offraw, MROWS, 256);
        gemm_k256<<<dim3(2, MROWS / 64), blk, 0, stream>>>(query, W_attn, b_attn, attnraw, MROWS, 128);

        float* accp = has_acc ? accbuf : out;
        ms_sample_f32<<<dim3((NBATCH * LQ * 8) / 4), blk, 0, stream>>>(
            value, offraw, attnraw, refpts, accp);

        if (has_acc)
            gemm_k256<<<dim3(4, MROWS / 64), blk, 0, stream>>>(accbuf, W_out, b_out, out, MROWS, 256);
        else
            outproj_inplace<<<dim3(MROWS / 32), blk, 0, stream>>>(out, W_out, b_out);
    }
}